// Round 1
// 805.137 us; speedup vs baseline: 1.0033x; 1.0033x over previous
//
#include <hip/hip_runtime.h>

#define B 32
#define F 1024
#define S 2048
#define KTOP 16
#define CHUNKS 32
#define ROWS_PER_CHUNK (S / CHUNKS) /* 64 */

// Kernel A: partial column sums of w over row-chunks.
// 256 threads * float4 = 1024 columns per block; grid = B * (S/1024) * CHUNKS = 2048
// blocks -> 8 blocks/CU (full 32 waves/CU). Each block streams 64 rows x 4 KiB.
__global__ void colsum_partial(const float* __restrict__ w, float* __restrict__ partial) {
    int bid = blockIdx.x;
    int chunk = bid % CHUNKS;
    int cg = (bid / CHUNKS) % (S / 1024);
    int b = bid / (CHUNKS * (S / 1024));
    int col = cg * 1024 + threadIdx.x * 4;
    size_t base = (size_t)b * S * S + (size_t)chunk * ROWS_PER_CHUNK * S + col;
    float4 acc = make_float4(0.f, 0.f, 0.f, 0.f);
#pragma unroll 8
    for (int i = 0; i < ROWS_PER_CHUNK; ++i) {
        float4 v = *(const float4*)(w + base + (size_t)i * S);
        acc.x += v.x; acc.y += v.y; acc.z += v.z; acc.w += v.w;
    }
    *(float4*)(partial + (size_t)(b * CHUNKS + chunk) * S + col) = acc;
}

// Kernel B (fused): fold CHUNKS partials -> column sums in LDS, then single-wave
// register-resident top-16 extraction (no barriers in the selection loop).
// Ties: lax.top_k semantics (equal value -> lower index wins).
__global__ void topk_fused(const float* __restrict__ partial, int* __restrict__ idx) {
    __shared__ float vals[S];
    int b = blockIdx.x;
    int tid = threadIdx.x;
    // Phase 1: 1024 threads reduce the CHUNKS partials; coalesced 4 KiB rows.
    for (int s = tid; s < S; s += 1024) {
        float acc = 0.f;
#pragma unroll
        for (int c = 0; c < CHUNKS; ++c) acc += partial[((size_t)(b * CHUNKS + c)) * S + s];
        vals[s] = acc;
    }
    __syncthreads();
    // Phase 2: wave 0 only. Each lane owns columns s = i*64 + lane, i in [0,32),
    // held in registers. Per pass: register scan -> shfl reduce -> clear winner.
    if (tid < 64) {
        float v[S / 64];
#pragma unroll
        for (int i = 0; i < S / 64; ++i) v[i] = vals[i * 64 + tid];
        for (int k = 0; k < KTOP; ++k) {
            float bv = v[0];
            int bi = tid; // s = 0*64 + tid
#pragma unroll
            for (int i = 1; i < S / 64; ++i) {
                int s = i * 64 + tid;
                if (v[i] > bv) { bv = v[i]; bi = s; } // strict > keeps lowest s per lane
            }
#pragma unroll
            for (int off = 32; off > 0; off >>= 1) {
                float ov = __shfl_down(bv, off);
                int oi = __shfl_down(bi, off);
                if (ov > bv || (ov == bv && oi < bi)) { bv = ov; bi = oi; }
            }
            bi = __shfl(bi, 0); // broadcast winner index from lane 0
            if (tid == 0) idx[b * KTOP + k] = bi;
            // clear winner in the owning lane's register file (static indices only)
#pragma unroll
            for (int i = 0; i < S / 64; ++i)
                if (i * 64 + tid == bi) v[i] = -1e30f;
        }
    }
}

// Kernel C: out[b][f][k] = x[b][f][idx[b][k]]. Coalesced writes; scattered reads via L2.
__global__ void gather_kernel(const float* __restrict__ x, const int* __restrict__ idx,
                              float* __restrict__ out) {
    int t = blockIdx.x * blockDim.x + threadIdx.x; // 0 .. B*F*KTOP-1
    int k = t % KTOP;
    int f = (t / KTOP) % F;
    int b = t / (KTOP * F);
    int j = idx[b * KTOP + k];
    out[t] = x[((size_t)b * F + f) * S + j];
}

extern "C" void kernel_launch(void* const* d_in, const int* in_sizes, int n_in,
                              void* d_out, int out_size, void* d_ws, size_t ws_size,
                              hipStream_t stream) {
    const float* x = (const float*)d_in[0];
    const float* w = (const float*)d_in[1];
    float* out = (float*)d_out;

    float* partial = (float*)d_ws;                  // B*CHUNKS*S floats = 8 MiB
    int* idx = (int*)(partial + (size_t)B * CHUNKS * S); // B*KTOP ints = 2 KiB

    colsum_partial<<<B * (S / 1024) * CHUNKS, 256, 0, stream>>>(w, partial);
    topk_fused<<<B, 1024, 0, stream>>>(partial, idx);
    gather_kernel<<<(B * F * KTOP) / 256, 256, 0, stream>>>(x, idx, out);
}